// Round 19
// baseline (46.521 us; speedup 1.0000x reference)
//
#include <hip/hip_runtime.h>

#define BATCH 4096
#define SEQ   80
#define EMBED 100
#define UNITS 64
#define NTILE (BATCH / 16)      // 256 batch tiles of 16 rows
#define NVOC  10000
#define NVWV  ((NVOC + 15) / 16)
#define NPAIR2 (SEQ / 2)

typedef float f32x4  __attribute__((ext_vector_type(4)));
typedef short bf16x8 __attribute__((ext_vector_type(8)));

#define MFMA16 __builtin_amdgcn_mfma_f32_16x16x32_bf16

// ---- ws layout (bytes) ----
#define TAB_OFF 0u           // bf16 table[10000][64] = 1,280,000 B (L2-resident)

__device__ __forceinline__ unsigned f2bfu(float f) {
    union { float f; unsigned u; } x; x.f = f;
    return (x.u + 0x7fffu + ((x.u >> 16) & 1u)) >> 16;   // RNE
}
__device__ __forceinline__ unsigned cvtpk(float lo, float hi) {
    unsigned r;
    asm("v_cvt_pk_bf16_f32 %0, %1, %2" : "=v"(r) : "v"(lo), "v"(hi));
    return r;
}
__device__ __forceinline__ float bflo(unsigned u) {
    union { unsigned u; float f; } x; x.u = u << 16; return x.f;
}
__device__ __forceinline__ float bfhi(unsigned u) {
    union { unsigned u; float f; } x; x.u = u & 0xffff0000u; return x.f;
}
// branch-free exact-tails tanh: 1 - 2/(e^{2x}+1)
__device__ __forceinline__ float fast_tanh(float x) {
    float e = __builtin_amdgcn_exp2f(x * 2.8853900817779268f);
    float r = __builtin_amdgcn_rcpf(e + 1.0f);
    return __builtin_fmaf(-2.0f, r, 1.0f);
}

// ---------------------------------------------------------------------------
// tableproj: table[v] = b1 + emb[v] @ W1 for all 10000 vocab rows (verified).
// ---------------------------------------------------------------------------
__global__ __launch_bounds__(256) void tableproj_kernel(
    const float* __restrict__ emb,
    const float* __restrict__ b1,
    const float* __restrict__ W1,
    char* __restrict__ table)
{
    const int lane = threadIdx.x & 63;
    const int wid  = threadIdx.x >> 6;
    const int gw   = blockIdx.x * 4 + wid;
    if (gw >= NVWV) return;
    const int m15  = lane & 15;
    const int kgrp = lane >> 4;
    const int v    = gw * 16 + m15;
    const int vc   = v < NVOC ? v : NVOC - 1;

    bf16x8 aW1[4][4];
    #pragma unroll
    for (int mt = 0; mt < 4; ++mt) {
        const int u = 16 * mt + m15;
        #pragma unroll
        for (int ks = 0; ks < 4; ++ks)
            #pragma unroll
            for (int j = 0; j < 8; ++j) {
                const int k = kgrp * 8 + j + 32 * ks;
                aW1[mt][ks][j] = (k < EMBED) ? (short)f2bfu(W1[k * UNITS + u])
                                             : (short)0;
            }
    }

    const float* rp = emb + (size_t)vc * EMBED;
    bf16x8 bf[4];
    #pragma unroll
    for (int ks = 0; ks < 3; ++ks) {
        f32x4 e0 = *(const f32x4*)(rp + kgrp * 8 + 32 * ks);
        f32x4 e1 = *(const f32x4*)(rp + kgrp * 8 + 32 * ks + 4);
        uint4 u;
        u.x = cvtpk(e0.x, e0.y); u.y = cvtpk(e0.z, e0.w);
        u.z = cvtpk(e1.x, e1.y); u.w = cvtpk(e1.z, e1.w);
        bf[ks] = *(bf16x8*)&u;
    }
    {
        uint4 u = {0u, 0u, 0u, 0u};
        if (kgrp == 0) {
            f32x4 e0 = *(const f32x4*)(rp + 96);
            u.x = cvtpk(e0.x, e0.y); u.y = cvtpk(e0.z, e0.w);
        }
        bf[3] = *(bf16x8*)&u;
    }

    f32x4 acc[4];
    #pragma unroll
    for (int mt = 0; mt < 4; ++mt)
        acc[mt] = *(const f32x4*)(b1 + 16 * mt + 4 * kgrp);
    #pragma unroll
    for (int ks = 0; ks < 4; ++ks)
        #pragma unroll
        for (int mt = 0; mt < 4; ++mt)
            acc[mt] = MFMA16(aW1[mt][ks], bf[ks], acc[mt], 0, 0, 0);

    #pragma unroll
    for (int mt = 0; mt < 4; ++mt) {
        uint2 q;
        q.x = cvtpk(acc[mt][0], acc[mt][1]);
        q.y = cvtpk(acc[mt][2], acc[mt][3]);
        *(uint2*)(table + (size_t)v * 128 + mt * 32 + kgrp * 8) = q;
    }
}

// ---------------------------------------------------------------------------
// rnn: register-feed scan, feed PINNED in VGPRs. Prologue gathers all 80
// xw fragments into xr[80]; an asm keep-alive fence forces them resident
// (compiler cannot sink the loads into the loop). Scan loop then has zero
// global memory ops. Scan body = verified R17/R18 PHASE.
// ---------------------------------------------------------------------------
__global__ __launch_bounds__(256, 1) void rnn_kernel(
    const int*    __restrict__ tokens,
    const uint2*  __restrict__ table,    // [10000][16] uint2
    const float*  __restrict__ U1,
    const float*  __restrict__ W2,
    const float*  __restrict__ U2,
    const float*  __restrict__ b2,
    const float*  __restrict__ Wo,
    const float*  __restrict__ bo,
    float*        __restrict__ out)
{
    __shared__ __align__(16) char h1L[2][2048];   // [buf][16b x 64u bf16, swz]
    __shared__ __align__(16) char h2L[2][2048];
    __shared__ int   tokL[16][84];                // pad 84: conflict-free
    __shared__ float headp[4][16];

    const int lane = threadIdx.x & 63;
    const int w    = threadIdx.x >> 6;
    const int m15  = lane & 15;
    const int kgrp = lane >> 4;
    const int swz  = (m15 & 7) << 4;
    const int wg   = blockIdx.x;

    // zero h2[-1] (buf 0) + cooperative token preload
    {
        uint4 z = {0u, 0u, 0u, 0u};
        if (threadIdx.x < 128) ((uint4*)h2L[0])[threadIdx.x] = z;
    }
    for (int i = threadIdx.x; i < 16 * SEQ; i += 256) {
        const int r = i / SEQ;
        const int t = i - r * SEQ;
        tokL[r][t] = tokens[(size_t)(wg * 16 + r) * SEQ + t];
    }

    // weight A-frags from f32 (latency hidden under gather prologue)
    const int urow = 16 * w + m15;
    bf16x8 aU1[2], aW2[2], aU2[2];
    #pragma unroll
    for (int ks = 0; ks < 2; ++ks)
        #pragma unroll
        for (int j = 0; j < 8; ++j) {
            const int k = kgrp * 8 + j + 32 * ks;
            aU1[ks][j] = (short)f2bfu(U1[k * UNITS + urow]);
            aW2[ks][j] = (short)f2bfu(W2[k * UNITS + urow]);
            aU2[ks][j] = (short)f2bfu(U2[k * UNITS + urow]);
        }
    const int ubase = 16 * w + 4 * kgrp;
    const f32x4 b2c = *(const f32x4*)(b2 + ubase);

    __syncthreads();   // tokL ready

    // ---- register feed: gather all 80 xw fragments, then PIN them ----
    const uint2* tabp = table + w * 4 + kgrp;
    uint2 xr[SEQ];
    #pragma unroll
    for (int t = 0; t < SEQ; ++t)
        xr[t] = tabp[(size_t)tokL[m15][t] * 16];
    // keep-alive fence: forces all gathers complete HERE and xr resident.
    #pragma unroll
    for (int t = 0; t < SEQ; ++t)
        asm volatile("" : "+v"(xr[t].x), "+v"(xr[t].y));

    // prologue: h1[0] = tanh(xw[0]) -> buf 0
    {
        float t0 = fast_tanh(bflo(xr[0].x)), t1 = fast_tanh(bfhi(xr[0].x));
        float t2 = fast_tanh(bflo(xr[0].y)), t3 = fast_tanh(bfhi(xr[0].y));
        uint2 pk; pk.x = cvtpk(t0, t1); pk.y = cvtpk(t2, t3);
        *(uint2*)(h1L[0] + m15 * 128 + ((32 * w + 8 * kgrp) ^ swz)) = pk;
    }
    asm volatile("s_waitcnt lgkmcnt(0)" ::: "memory");
    __builtin_amdgcn_s_barrier();

    float d2f0 = 0.f, d2f1 = 0.f, d2f2 = 0.f, d2f3 = 0.f;

#define LBAR() do { asm volatile("s_waitcnt lgkmcnt(0)" ::: "memory"); \
                    __builtin_amdgcn_s_barrier(); } while (0)
// One phase; Q2 = packed bf16 xw[T+1] (pinned register). Verified math.
#define PHASE(Q2, P, Q)                                                          \
  {                                                                              \
    bf16x8 bh1a = *(const bf16x8*)(h1L[P] + m15 * 128 + ((kgrp * 16     ) ^ swz)); \
    bf16x8 bh1b = *(const bf16x8*)(h1L[P] + m15 * 128 + ((kgrp * 16 + 64) ^ swz)); \
    bf16x8 bh2a = *(const bf16x8*)(h2L[P] + m15 * 128 + ((kgrp * 16     ) ^ swz)); \
    bf16x8 bh2b = *(const bf16x8*)(h2L[P] + m15 * 128 + ((kgrp * 16 + 64) ^ swz)); \
    f32x4 d1 = {bflo((Q2).x), bfhi((Q2).x), bflo((Q2).y), bfhi((Q2).y)};         \
    d1 = MFMA16(aU1[0], bh1a, d1, 0, 0, 0);                                      \
    d1 = MFMA16(aU1[1], bh1b, d1, 0, 0, 0);                                      \
    f32x4 dC = b2c;                                                              \
    dC = MFMA16(aW2[0], bh1a, dC, 0, 0, 0);                                      \
    dC = MFMA16(aW2[1], bh1b, dC, 0, 0, 0);                                      \
    f32x4 dD = {0.f, 0.f, 0.f, 0.f};                                             \
    dD = MFMA16(aU2[0], bh2a, dD, 0, 0, 0);                                      \
    dD = MFMA16(aU2[1], bh2b, dD, 0, 0, 0);                                      \
    float n0 = fast_tanh(d1[0]);                                                 \
    float n1 = fast_tanh(d1[1]);                                                 \
    float n2 = fast_tanh(d1[2]);                                                 \
    float n3 = fast_tanh(d1[3]);                                                 \
    d2f0 = fast_tanh(dC[0] + dD[0]);                                             \
    d2f1 = fast_tanh(dC[1] + dD[1]);                                             \
    d2f2 = fast_tanh(dC[2] + dD[2]);                                             \
    d2f3 = fast_tanh(dC[3] + dD[3]);                                             \
    {                                                                            \
        uint2 pk; pk.x = cvtpk(n0, n1); pk.y = cvtpk(n2, n3);                    \
        *(uint2*)(h1L[Q] + m15 * 128 + ((32 * w + 8 * kgrp) ^ swz)) = pk;        \
    }                                                                            \
    {                                                                            \
        uint2 pk; pk.x = cvtpk(d2f0, d2f1); pk.y = cvtpk(d2f2, d2f3);            \
        *(uint2*)(h2L[Q] + m15 * 128 + ((32 * w + 8 * kgrp) ^ swz)) = pk;        \
    }                                                                            \
    LBAR();                                                                      \
  }

    #pragma unroll
    for (int k = 0; k < NPAIR2; ++k) {
        PHASE(xr[2 * k + 1], 0, 1)                               // phase 2k
        PHASE(xr[(2 * k + 2 < SEQ) ? 2 * k + 2 : SEQ - 1], 1, 0) // phase 2k+1
    }
#undef PHASE
#undef LBAR

    // ---- head: out[b] = sigmoid(h2[79] @ Wo + bo) ----
    const f32x4 woc = *(const f32x4*)(Wo + ubase);
    float p = d2f0 * woc[0] + d2f1 * woc[1] + d2f2 * woc[2] + d2f3 * woc[3];
    p += __shfl_xor(p, 16, 64);
    p += __shfl_xor(p, 32, 64);
    if (lane < 16) headp[w][lane] = p;
    __syncthreads();
    if (threadIdx.x < 16) {
        const float z = headp[0][threadIdx.x] + headp[1][threadIdx.x]
                      + headp[2][threadIdx.x] + headp[3][threadIdx.x] + bo[0];
        const float e = __builtin_amdgcn_exp2f(-z * 1.4426950408889634f);
        out[wg * 16 + threadIdx.x] = __builtin_amdgcn_rcpf(1.0f + e);
    }
}

extern "C" void kernel_launch(void* const* d_in, const int* in_sizes, int n_in,
                              void* d_out, int out_size, void* d_ws, size_t ws_size,
                              hipStream_t stream) {
    const int*   tokens = (const int*)  d_in[0];
    const float* emb    = (const float*)d_in[1];
    const float* W1     = (const float*)d_in[2];
    const float* U1     = (const float*)d_in[3];
    const float* b1     = (const float*)d_in[4];
    const float* W2     = (const float*)d_in[5];
    const float* U2     = (const float*)d_in[6];
    const float* b2     = (const float*)d_in[7];
    const float* Wo     = (const float*)d_in[8];
    const float* bo     = (const float*)d_in[9];
    float* out = (float*)d_out;
    char*  ws  = (char*)d_ws;

    tableproj_kernel<<<(NVWV + 3) / 4, 256, 0, stream>>>(
        emb, b1, W1, ws + TAB_OFF);
    rnn_kernel<<<NTILE, 256, 0, stream>>>(
        tokens, (const uint2*)(ws + TAB_OFF),
        U1, W2, U2, b2, Wo, bo, out);
}